// Round 9
// baseline (46.812 us; speedup 1.0000x reference)
//
#include <hip/hip_runtime.h>
#include <math.h>

// Problem size: B*C*H*W = 64*1*512*512
#define N_TOTAL   16777216
#define ACC_COUNT 5        // sx, st, sx2, sxt, sb(log2-space)  (st2 == st since t in {0,1})
#define BLOCK     256
#define F4_PER_THREAD 8    // 8 float4 per array per thread, in 2 batches of 4
#define GRID  (N_TOTAL / 4 / BLOCK / F4_PER_THREAD)   // 2048 blocks == exact wave capacity

// t is EXACTLY 0.0f or 1.0f, so the BCE blend selects one term:
//   max(log(t ? x : 1-x), -100)  ==  ln2 * max(log2(arg), -100/ln2)
#define ELEM_BODY(x, t)                                        \
    do {                                                       \
        float omx = 1.0f - (x);                                \
        sx += (x);                                             \
        st += (t);                                             \
        sx2 = fmaf((x), (x), sx2);                             \
        sxt = fmaf((x), (t), sxt);                             \
        float arg = fmaf((t), (x) - omx, omx); /* t?x:1-x */   \
        float l2  = fmaxf(__log2f(arg), -144.26950408889634f); \
        sb += l2;                                              \
    } while (0)

#define ELEM4(xv, tv)              \
    do {                           \
        ELEM_BODY((xv).x, (tv).x); \
        ELEM_BODY((xv).y, (tv).y); \
        ELEM_BODY((xv).z, (tv).z); \
        ELEM_BODY((xv).w, (tv).w); \
    } while (0)

__device__ __forceinline__ double sum4(float4 v) {
    return ((double)v.x + (double)v.y) + ((double)v.z + (double)v.w);
}

__global__ __launch_bounds__(BLOCK) void loss_fused_kernel(
    const float4* __restrict__ x4,
    const float4* __restrict__ t4,
    float* __restrict__ partials,        // SoA: partials[k*GRID + blk]
    unsigned int* __restrict__ counter,  // zeroed by host each call
    float* __restrict__ out)
{
    float sx = 0.f, st = 0.f, sx2 = 0.f, sxt = 0.f, sb = 0.f;

    const int base = blockIdx.x * (BLOCK * F4_PER_THREAD) + threadIdx.x;

    // Two batches of (4 x-loads + 4 t-loads): 8 independent 16B loads in
    // flight per batch; VGPR stays low enough for 8 waves/SIMD.
    #pragma unroll 2
    for (int b = 0; b < 2; ++b) {
        const int o = base + b * (4 * BLOCK);
        float4 xv0 = x4[o];
        float4 xv1 = x4[o + BLOCK];
        float4 xv2 = x4[o + 2 * BLOCK];
        float4 xv3 = x4[o + 3 * BLOCK];
        float4 tv0 = t4[o];
        float4 tv1 = t4[o + BLOCK];
        float4 tv2 = t4[o + 2 * BLOCK];
        float4 tv3 = t4[o + 3 * BLOCK];

        ELEM4(xv0, tv0);
        ELEM4(xv1, tv1);
        ELEM4(xv2, tv2);
        ELEM4(xv3, tv3);
    }

    // ---- wave (64-lane) reduction ----
    #pragma unroll
    for (int off = 32; off > 0; off >>= 1) {
        sx  += __shfl_down(sx,  off);
        st  += __shfl_down(st,  off);
        sx2 += __shfl_down(sx2, off);
        sxt += __shfl_down(sxt, off);
        sb  += __shfl_down(sb,  off);
    }

    // ---- block reduction across 4 waves ----
    __shared__ float lds[4][ACC_COUNT];
    const int lane = threadIdx.x & 63;
    const int wid  = threadIdx.x >> 6;
    if (lane == 0) {
        lds[wid][0] = sx;  lds[wid][1] = st;  lds[wid][2] = sx2;
        lds[wid][3] = sxt; lds[wid][4] = sb;
    }
    __syncthreads();

    // ---- publish 5 partials with agent-scope atomic stores (write-through
    // to the coherence point; NO per-block fence — this is what r5 got wrong)
    if (threadIdx.x < ACC_COUNT) {
        const int k = threadIdx.x;
        float v = lds[0][k] + lds[1][k] + lds[2][k] + lds[3][k];
        __hip_atomic_store(&partials[k * GRID + blockIdx.x], v,
                           __ATOMIC_RELAXED, __HIP_MEMORY_SCOPE_AGENT);
    }
    // Compiler drains vmcnt(0) before s_barrier => the atomic stores above
    // have reached the coherence point before any thread passes this barrier.
    __syncthreads();

    // ---- ticket: last-arriving block finalizes ----
    __shared__ int is_last;
    if (threadIdx.x == 0) {
        unsigned int prev = __hip_atomic_fetch_add(
            counter, 1u, __ATOMIC_RELAXED, __HIP_MEMORY_SCOPE_AGENT);
        is_last = (prev == (unsigned int)(GRID - 1));
    }
    __syncthreads();
    if (!is_last) return;

    // ONE acquire fence, in ONE block: invalidate stale L1/L2 lines so the
    // plain float4 reads below observe every block's published partials.
    __threadfence();

    // ---- finalize: 256 threads, 2 float4 per row each (GRID/4 = 512 f4/row)
    const float4* p4 = (const float4*)partials;
    const int row_f4 = GRID / 4;   // 512

    double a[ACC_COUNT];
    #pragma unroll
    for (int k = 0; k < ACC_COUNT; ++k) {
        float4 v0 = p4[k * row_f4 + threadIdx.x];
        float4 v1 = p4[k * row_f4 + threadIdx.x + BLOCK];
        a[k] = sum4(v0) + sum4(v1);
    }

    #pragma unroll
    for (int off = 32; off > 0; off >>= 1) {
        #pragma unroll
        for (int k = 0; k < ACC_COUNT; ++k)
            a[k] += __shfl_down(a[k], off);
    }

    __shared__ double dlds[4][ACC_COUNT];
    if (lane == 0) {
        #pragma unroll
        for (int k = 0; k < ACC_COUNT; ++k) dlds[wid][k] = a[k];
    }
    __syncthreads();

    if (threadIdx.x == 0) {
        double fsx  = dlds[0][0] + dlds[1][0] + dlds[2][0] + dlds[3][0];
        double fst  = dlds[0][1] + dlds[1][1] + dlds[2][1] + dlds[3][1];
        double fsx2 = dlds[0][2] + dlds[1][2] + dlds[2][2] + dlds[3][2];
        double fsxt = dlds[0][3] + dlds[1][3] + dlds[2][3] + dlds[3][3];
        double fsb  = dlds[0][4] + dlds[1][4] + dlds[2][4] + dlds[3][4];

        const double n = (double)N_TOTAL;
        const double LN2 = 0.6931471805599453;

        // BCE (fsb is in log2 space)
        double bce = -(fsb * LN2) / n;

        // NCC (Σt² == Σt exactly, since t ∈ {0,1})
        double xm = fsx / n;
        double tm = fst / n;
        double xs = sqrt((fsx2 - fsx * fsx / n) / (n - 1.0));
        double ts = sqrt((fst  - fst * fst / n) / (n - 1.0));
        double ncc = (fsxt - n * xm * tm) / (xs * ts * n);

        // Tversky
        const double beta = 0.1, adding = 1.0;
        double TP = fsxt;
        double FP = fsx - fsxt;
        double FN = fst - fsxt;
        double tversky = (TP + adding) / (TP + beta * FP + (1.0 - beta) * FN + adding);

        const double alpha = 0.5;
        double res = (1.0 - (alpha * ncc + (1.0 - alpha) * tversky)) * bce;

        out[0] = (float)res;
    }
}

extern "C" void kernel_launch(void* const* d_in, const int* in_sizes, int n_in,
                              void* d_out, int out_size, void* d_ws, size_t ws_size,
                              hipStream_t stream)
{
    const float* x = (const float*)d_in[0];
    const float* t = (const float*)d_in[1];
    float* out = (float*)d_out;

    float* partials = (float*)d_ws;   // ACC_COUNT * GRID floats = 40 KB
    unsigned int* counter =
        (unsigned int*)((char*)d_ws + ACC_COUNT * GRID * sizeof(float));

    // d_ws is NOT re-poisoned between replays — zero the ticket each call.
    hipMemsetAsync(counter, 0, sizeof(unsigned int), stream);

    loss_fused_kernel<<<GRID, BLOCK, 0, stream>>>(
        (const float4*)x, (const float4*)t, partials, counter, out);
}

// Round 10
// 28.058 us; speedup vs baseline: 1.6684x; 1.6684x over previous
//
#include <hip/hip_runtime.h>
#include <math.h>

// Problem size: B*C*H*W = 64*1*512*512
#define N_TOTAL   16777216
#define ACC_COUNT 5        // sx, st, sx2, sxt, sb(log2-space)  (st2 == st since t in {0,1})
#define BLOCK     256
#define F4_PER_THREAD 8    // 8 float4 per array per thread, in 2 batches of 4
#define GRID  (N_TOTAL / 4 / BLOCK / F4_PER_THREAD)   // 2048 blocks
#define FIN_BLOCK 512      // finalize: 512 thr × float4 = 2048 partials in ONE round

// t is EXACTLY 0.0f or 1.0f, so the BCE blend selects one term:
//   max(log(t ? x : 1-x), -100)  ==  ln2 * max(log2(arg), -100/ln2)
#define ELEM_BODY(x, t)                                        \
    do {                                                       \
        float omx = 1.0f - (x);                                \
        sx += (x);                                             \
        st += (t);                                             \
        sx2 = fmaf((x), (x), sx2);                             \
        sxt = fmaf((x), (t), sxt);                             \
        float arg = fmaf((t), (x) - omx, omx); /* t?x:1-x */   \
        float l2  = fmaxf(__log2f(arg), -144.26950408889634f); \
        sb += l2;                                              \
    } while (0)

#define ELEM4(xv, tv)              \
    do {                           \
        ELEM_BODY((xv).x, (tv).x); \
        ELEM_BODY((xv).y, (tv).y); \
        ELEM_BODY((xv).z, (tv).z); \
        ELEM_BODY((xv).w, (tv).w); \
    } while (0)

__global__ __launch_bounds__(BLOCK) void loss_reduce_kernel(
    const float4* __restrict__ x4,
    const float4* __restrict__ t4,
    float* __restrict__ partials)   // SoA: partials[k*GRID + blockIdx.x]
{
    float sx = 0.f, st = 0.f, sx2 = 0.f, sxt = 0.f, sb = 0.f;

    const int base = blockIdx.x * (BLOCK * F4_PER_THREAD) + threadIdx.x;

    // Two batches of (4 x-loads + 4 t-loads): 8 independent 16B loads in
    // flight per batch; VGPR stays low enough for 8 waves/SIMD.
    #pragma unroll 2
    for (int b = 0; b < 2; ++b) {
        const int o = base + b * (4 * BLOCK);
        float4 xv0 = x4[o];
        float4 xv1 = x4[o + BLOCK];
        float4 xv2 = x4[o + 2 * BLOCK];
        float4 xv3 = x4[o + 3 * BLOCK];
        float4 tv0 = t4[o];
        float4 tv1 = t4[o + BLOCK];
        float4 tv2 = t4[o + 2 * BLOCK];
        float4 tv3 = t4[o + 3 * BLOCK];

        ELEM4(xv0, tv0);
        ELEM4(xv1, tv1);
        ELEM4(xv2, tv2);
        ELEM4(xv3, tv3);
    }

    // ---- wave (64-lane) reduction ----
    #pragma unroll
    for (int off = 32; off > 0; off >>= 1) {
        sx  += __shfl_down(sx,  off);
        st  += __shfl_down(st,  off);
        sx2 += __shfl_down(sx2, off);
        sxt += __shfl_down(sxt, off);
        sb  += __shfl_down(sb,  off);
    }

    // ---- block reduction across 4 waves ----
    __shared__ float lds[4][ACC_COUNT];
    int lane = threadIdx.x & 63;
    int wid  = threadIdx.x >> 6;
    if (lane == 0) {
        lds[wid][0] = sx;  lds[wid][1] = st;  lds[wid][2] = sx2;
        lds[wid][3] = sxt; lds[wid][4] = sb;
    }
    __syncthreads();

    if (threadIdx.x < ACC_COUNT) {
        int k = threadIdx.x;
        float v = lds[0][k] + lds[1][k] + lds[2][k] + lds[3][k];
        partials[k * GRID + blockIdx.x] = v;   // plain store, no atomics
    }
}

__global__ __launch_bounds__(FIN_BLOCK) void loss_finalize_kernel(
    const float4* __restrict__ partials4,   // same buffer, viewed as float4
    float* __restrict__ out)
{
    // GRID = 2048 partials per accumulator row; 512 threads × float4 = one round.
    const int tid = threadIdx.x;
    const int row_f4 = GRID / 4;   // 512 float4 per row

    double a[ACC_COUNT];
    #pragma unroll
    for (int k = 0; k < ACC_COUNT; ++k) {
        float4 v = partials4[k * row_f4 + tid];   // 5 independent 16B loads
        a[k] = (double)v.x + (double)v.y + (double)v.z + (double)v.w;
    }

    // ---- wave (64-lane) reduction of 5 doubles ----
    #pragma unroll
    for (int off = 32; off > 0; off >>= 1) {
        #pragma unroll
        for (int k = 0; k < ACC_COUNT; ++k)
            a[k] += __shfl_down(a[k], off);
    }

    // ---- block reduction across 8 waves ----
    __shared__ double lds[8][ACC_COUNT];
    int lane = tid & 63;
    int wid  = tid >> 6;
    if (lane == 0) {
        #pragma unroll
        for (int k = 0; k < ACC_COUNT; ++k) lds[wid][k] = a[k];
    }
    __syncthreads();

    if (tid == 0) {
        double s[ACC_COUNT] = {0, 0, 0, 0, 0};
        #pragma unroll
        for (int w = 0; w < 8; ++w)
            #pragma unroll
            for (int k = 0; k < ACC_COUNT; ++k)
                s[k] += lds[w][k];

        double sx  = s[0];
        double st  = s[1];
        double sx2 = s[2];
        double sxt = s[3];
        double sb  = s[4];

        const double n = (double)N_TOTAL;
        const double LN2 = 0.6931471805599453;

        // BCE (sb is in log2 space)
        double bce = -(sb * LN2) / n;

        // NCC (Σt² == Σt exactly, since t ∈ {0,1})
        double xm = sx / n;
        double tm = st / n;
        double xs = sqrt((sx2 - sx * sx / n) / (n - 1.0));
        double ts = sqrt((st  - st * st / n) / (n - 1.0));
        double ncc = (sxt - n * xm * tm) / (xs * ts * n);

        // Tversky
        const double beta = 0.1, adding = 1.0;
        double TP = sxt;
        double FP = sx - sxt;
        double FN = st - sxt;
        double tversky = (TP + adding) / (TP + beta * FP + (1.0 - beta) * FN + adding);

        const double alpha = 0.5;
        double res = (1.0 - (alpha * ncc + (1.0 - alpha) * tversky)) * bce;

        out[0] = (float)res;
    }
}

extern "C" void kernel_launch(void* const* d_in, const int* in_sizes, int n_in,
                              void* d_out, int out_size, void* d_ws, size_t ws_size,
                              hipStream_t stream)
{
    const float* x = (const float*)d_in[0];
    const float* t = (const float*)d_in[1];
    float* out = (float*)d_out;
    float* partials = (float*)d_ws;    // ACC_COUNT * GRID floats = 40 KB (16B-aligned)

    loss_reduce_kernel<<<GRID, BLOCK, 0, stream>>>(
        (const float4*)x, (const float4*)t, partials);
    loss_finalize_kernel<<<1, FIN_BLOCK, 0, stream>>>(
        (const float4*)partials, out);
}